// Round 2
// baseline (1126.985 us; speedup 1.0000x reference)
//
#include <hip/hip_runtime.h>

#define E_EDGES 1000000
#define N_NODES 100000
#define HID 128

// ---- workspace layout (bytes) ----
// 0    : counts[8]  (int)   -- per-combo edge counts (memset 0)
// 32   : cursor[8]  (int)   -- scatter cursors       (memset 0)
// 64   : seg[8]     (int)   -- padded segment starts (edges)
// 96   : tile[8]    (int)   -- segment starts in 32-edge tiles; tile[6]=total
// 256  : cmb[E]     (int8)  -- combo id per edge (-1 invalid)
// WS_LIST : list[E + 384] (int) -- bucketed edge ids, pad slots = -1 (memset 0xFF)
// WS_W1F  : w1 bf16 frags  6*12*8*64*8
// WS_W2F  : w2 bf16 frags  6*4*8*64*8
static constexpr int    WS_CMB  = 256;
static constexpr int    WS_LIST = 1000448;
static constexpr int    WS_W1F  = 5001984;
static constexpr int    WS_W2F  = 5591808;

typedef __bf16 bf16x8 __attribute__((ext_vector_type(8)));
typedef float  f32x4  __attribute__((ext_vector_type(4)));

__device__ __forceinline__ unsigned short f2bf(float f) {
    unsigned int u = __builtin_bit_cast(unsigned int, f);
    u = (u + 0x7FFFu + ((u >> 16) & 1u)) >> 16;   // RNE
    return (unsigned short)u;
}

// ---------------- weight conversion: fp32 -> bf16 MFMA B-frag layout ----------------
// w1f flat idx: ((c*12+kt)*8+nt)*64*8 + lane*8 + j  ; element = W[k=kt*32+(lane>>4)*8+j][n=nt*16+(lane&15)]
__global__ void k_wconv(const float* __restrict__ W1, const float* __restrict__ W2,
                        unsigned short* __restrict__ w1f, unsigned short* __restrict__ w2f) {
    int idx = blockIdx.x * 256 + threadIdx.x;
    if (idx < 294912) {
        int j = idx & 7, lane = (idx >> 3) & 63, nt = (idx >> 9) & 7;
        int t = idx >> 12;            // 0..71
        int c = t / 12, kt = t - c * 12;
        int k = kt * 32 + ((lane >> 4) << 3) + j;
        int n = (nt << 4) + (lane & 15);
        w1f[idx] = f2bf(W1[(c * 384 + k) * 128 + n]);
    } else {
        int i2 = idx - 294912;        // < 98304
        int j = i2 & 7, lane = (i2 >> 3) & 63, nt = (i2 >> 9) & 7;
        int t = i2 >> 12;             // 0..23
        int c = t >> 2, kt = t & 3;
        int k = kt * 32 + ((lane >> 4) << 3) + j;
        int n = (nt << 4) + (lane & 15);
        w2f[i2] = f2bf(W2[(c * 128 + k) * 128 + n]);
    }
}

// ---------------- classify edges, count per combo, zero invalid outputs ----------------
__global__ void k_classify(const int* __restrict__ ei, const int* __restrict__ vol,
                           signed char* __restrict__ cmb, float* __restrict__ out,
                           int* __restrict__ counts) {
    __shared__ int bc[6];
    int tid = threadIdx.x;
    if (tid < 6) bc[tid] = 0;
    __syncthreads();
    int eid = blockIdx.x * 256 + tid;
    if (eid < E_EDGES) {
        int s = ei[eid], t = ei[E_EDGES + eid];
        int gs = vol[s] / 3, ge = vol[t] / 3;     // volume 0..8 -> group 0..2
        int cc = -1;
        if (gs <= ge) cc = (gs == 0 ? 0 : (gs == 1 ? 2 : 3)) + ge;  // (0,0)(0,1)(0,2)(1,1)(1,2)(2,2)
        cmb[eid] = (signed char)cc;
        if (cc < 0) out[eid] = 0.f;
        else atomicAdd(&bc[cc], 1);
    }
    __syncthreads();
    if (tid < 6 && bc[tid] > 0) atomicAdd(&counts[tid], bc[tid]);
}

// ---------------- segment offsets (pad each combo to multiple of 32) ----------------
__global__ void k_offsets(int* __restrict__ ws) {
    if (threadIdx.x == 0 && blockIdx.x == 0) {
        int* counts = ws;        // ints 0..7
        int* seg    = ws + 16;   // byte 64
        int* tile   = ws + 24;   // byte 96
        int acc = 0;
        for (int c = 0; c < 6; ++c) {
            seg[c]  = acc;
            tile[c] = acc >> 5;
            acc += ((counts[c] + 31) >> 5) << 5;
        }
        seg[6]  = acc;
        tile[6] = acc >> 5;      // total 32-edge tiles
    }
}

// ---------------- scatter edge ids into combo buckets ----------------
__global__ void k_scatter(const signed char* __restrict__ cmb, int* __restrict__ list,
                          const int* __restrict__ seg, int* __restrict__ cursor) {
    __shared__ int bc[6], basep[6];
    int tid = threadIdx.x;
    if (tid < 6) bc[tid] = 0;
    __syncthreads();
    int eid = blockIdx.x * 256 + tid;
    int cc = -1, lp = 0;
    if (eid < E_EDGES) {
        cc = cmb[eid];
        if (cc >= 0) lp = atomicAdd(&bc[cc], 1);
    }
    __syncthreads();
    if (tid < 6) basep[tid] = bc[tid] > 0 ? atomicAdd(&cursor[tid], bc[tid]) : 0;
    __syncthreads();
    if (cc >= 0) list[seg[cc] + basep[cc] + lp] = eid;
}

// ---------------- LN1 + relu -> bf16 into per-wave LDS region ----------------
__device__ __forceinline__ void ln1_store(f32x4* acc, const float* __restrict__ b1,
    const float* __restrict__ g1, const float* __restrict__ be1,
    int cb, int colb, int quad, unsigned short* hrow) {
    float sum[4] = {0,0,0,0}, sq[4] = {0,0,0,0};
#pragma unroll
    for (int nt = 0; nt < 8; ++nt) {
        float bb = b1[cb + colb + nt * 16];
#pragma unroll
        for (int r = 0; r < 4; ++r) {
            float v = acc[nt][r] + bb;
            acc[nt][r] = v; sum[r] += v; sq[r] += v * v;
        }
    }
#pragma unroll
    for (int m = 1; m < 16; m <<= 1)
#pragma unroll
        for (int r = 0; r < 4; ++r) {
            sum[r] += __shfl_xor(sum[r], m);
            sq[r]  += __shfl_xor(sq[r], m);
        }
    float mu[4], rs[4];
#pragma unroll
    for (int r = 0; r < 4; ++r) {
        mu[r] = sum[r] * 0.0078125f;
        float var = sq[r] * 0.0078125f - mu[r] * mu[r];
        rs[r] = rsqrtf(var + 1e-5f);
    }
#pragma unroll
    for (int nt = 0; nt < 8; ++nt) {
        float gg = g1[cb + colb + nt * 16], ee = be1[cb + colb + nt * 16];
#pragma unroll
        for (int r = 0; r < 4; ++r) {
            float v = (acc[nt][r] - mu[r]) * rs[r] * gg + ee;
            v = fmaxf(v, 0.f);
            hrow[(quad * 4 + r) * 136 + colb + nt * 16] =
                __builtin_bit_cast(unsigned short, (__bf16)v);
        }
    }
}

// ---------------- LN2 + relu + W3 dot; returns logit (minus b3) for row colb ----------------
__device__ __forceinline__ float ln2_dot(f32x4* acc, const float* __restrict__ b2,
    const float* __restrict__ g2, const float* __restrict__ be2,
    const float* __restrict__ W3, int cb, int colb, int quad) {
    float sum[4] = {0,0,0,0}, sq[4] = {0,0,0,0};
#pragma unroll
    for (int nt = 0; nt < 8; ++nt) {
        float bb = b2[cb + colb + nt * 16];
#pragma unroll
        for (int r = 0; r < 4; ++r) {
            float v = acc[nt][r] + bb;
            acc[nt][r] = v; sum[r] += v; sq[r] += v * v;
        }
    }
#pragma unroll
    for (int m = 1; m < 16; m <<= 1)
#pragma unroll
        for (int r = 0; r < 4; ++r) {
            sum[r] += __shfl_xor(sum[r], m);
            sq[r]  += __shfl_xor(sq[r], m);
        }
    float mu[4], rs[4];
#pragma unroll
    for (int r = 0; r < 4; ++r) {
        mu[r] = sum[r] * 0.0078125f;
        float var = sq[r] * 0.0078125f - mu[r] * mu[r];
        rs[r] = rsqrtf(var + 1e-5f);
    }
    float part[4] = {0,0,0,0};
#pragma unroll
    for (int nt = 0; nt < 8; ++nt) {
        float gg = g2[cb + colb + nt * 16], ee = be2[cb + colb + nt * 16];
        float w3 = W3[cb + colb + nt * 16];
#pragma unroll
        for (int r = 0; r < 4; ++r) {
            float v = (acc[nt][r] - mu[r]) * rs[r] * gg + ee;
            v = fmaxf(v, 0.f);
            part[r] += v * w3;
        }
    }
#pragma unroll
    for (int m = 1; m < 16; m <<= 1)
#pragma unroll
        for (int r = 0; r < 4; ++r) part[r] += __shfl_xor(part[r], m);
    // row colb lives in quad (colb>>2), reg (colb&3); broadcast cross-quad
    float vout = 0.f;
#pragma unroll
    for (int r = 0; r < 4; ++r) {
        float t = __shfl(part[r], (colb >> 2) << 4);
        if ((colb & 3) == r) vout = t;
    }
    return vout;
}

// ---------------- fused MLP: one wave = 32 edges of one combo, no barriers ----------------
__global__ __launch_bounds__(256, 4) void k_mlp(
    const float* __restrict__ x, const int* __restrict__ ei, const float* __restrict__ efeat,
    const int* __restrict__ tile_tab, const int* __restrict__ list,
    const unsigned short* __restrict__ w1f, const unsigned short* __restrict__ w2f,
    const float* __restrict__ b1, const float* __restrict__ g1, const float* __restrict__ be1,
    const float* __restrict__ b2, const float* __restrict__ g2, const float* __restrict__ be2,
    const float* __restrict__ W3, const float* __restrict__ b3,
    float* __restrict__ out)
{
    __shared__ unsigned short H1[4 * 4352];   // per-wave 32 rows x stride 136 (bf16)

    int tid  = threadIdx.x;
    int wv   = tid >> 6, lane = tid & 63;
    int colb = lane & 15, quad = lane >> 4;

    int t32 = blockIdx.x * 4 + wv;
    if (t32 >= tile_tab[6]) return;
    int c = 0;
#pragma unroll
    for (int k = 1; k < 6; ++k) c += (t32 >= tile_tab[k]);

    int lb = t32 * 32;
    int f  = list[lb];                 // first edge of tile: always valid
    int e0 = list[lb + colb];
    int e1 = list[lb + 16 + colb];
    int a0 = e0 >= 0 ? e0 : f;
    int a1 = e1 >= 0 ? e1 : f;

    int s0 = ei[a0], t0 = ei[E_EDGES + a0];
    int s1 = ei[a1], t1 = ei[E_EDGES + a1];
    const float* base0[3] = { x + (size_t)s0 * 128, x + (size_t)t0 * 128, efeat + (size_t)a0 * 128 };
    const float* base1[3] = { x + (size_t)s1 * 128, x + (size_t)t1 * 128, efeat + (size_t)a1 * 128 };

    const bf16x8* w1v = (const bf16x8*)w1f;
    const bf16x8* w2v = (const bf16x8*)w2f;
    const f32x4 zero4 = {0.f, 0.f, 0.f, 0.f};
    int cb = c * 128;

    // ---- layer 1: two 16-row A-frags share each B-frag ----
    f32x4 acc0[8], acc1[8];
#pragma unroll
    for (int nt = 0; nt < 8; ++nt) { acc0[nt] = zero4; acc1[nt] = zero4; }

    float4 p00, p01, p10, p11;
    {
        const float4* q0 = (const float4*)(base0[0] + quad * 8);
        p00 = q0[0]; p01 = q0[1];
        const float4* q1 = (const float4*)(base1[0] + quad * 8);
        p10 = q1[0]; p11 = q1[1];
    }
#pragma unroll
    for (int kt = 0; kt < 12; ++kt) {
        float4 n00, n01, n10, n11;
        if (kt < 11) {
            int k1 = kt + 1, sec = k1 >> 2, ko = k1 & 3;
            const float4* q0 = (const float4*)(base0[sec] + ko * 32 + quad * 8);
            n00 = q0[0]; n01 = q0[1];
            const float4* q1 = (const float4*)(base1[sec] + ko * 32 + quad * 8);
            n10 = q1[0]; n11 = q1[1];
        }
        bf16x8 af0, af1;
        af0[0] = (__bf16)p00.x; af0[1] = (__bf16)p00.y; af0[2] = (__bf16)p00.z; af0[3] = (__bf16)p00.w;
        af0[4] = (__bf16)p01.x; af0[5] = (__bf16)p01.y; af0[6] = (__bf16)p01.z; af0[7] = (__bf16)p01.w;
        af1[0] = (__bf16)p10.x; af1[1] = (__bf16)p10.y; af1[2] = (__bf16)p10.z; af1[3] = (__bf16)p10.w;
        af1[4] = (__bf16)p11.x; af1[5] = (__bf16)p11.y; af1[6] = (__bf16)p11.z; af1[7] = (__bf16)p11.w;
        int wbase = c * 6144 + kt * 512 + lane;
#pragma unroll
        for (int nt = 0; nt < 8; ++nt) {
            bf16x8 bf = w1v[wbase + nt * 64];
            acc0[nt] = __builtin_amdgcn_mfma_f32_16x16x32_bf16(af0, bf, acc0[nt], 0, 0, 0);
            acc1[nt] = __builtin_amdgcn_mfma_f32_16x16x32_bf16(af1, bf, acc1[nt], 0, 0, 0);
        }
        p00 = n00; p01 = n01; p10 = n10; p11 = n11;
    }

    // ---- LN1 + relu -> h1 (bf16) in this wave's LDS region ----
    unsigned short* hg0 = &H1[wv * 4352];          // rows 0..15
    unsigned short* hg1 = &H1[wv * 4352 + 16 * 136]; // rows 16..31
    ln1_store(acc0, b1, g1, be1, cb, colb, quad, hg0);
    ln1_store(acc1, b1, g1, be1, cb, colb, quad, hg1);

    // ---- layer 2 (same-wave LDS RAW; compiler inserts lgkmcnt waits) ----
#pragma unroll
    for (int nt = 0; nt < 8; ++nt) { acc0[nt] = zero4; acc1[nt] = zero4; }
#pragma unroll
    for (int kt = 0; kt < 4; ++kt) {
        bf16x8 af0 = *(const bf16x8*)&hg0[colb * 136 + quad * 8 + kt * 32];
        bf16x8 af1 = *(const bf16x8*)&hg1[colb * 136 + quad * 8 + kt * 32];
        int wbase = c * 2048 + kt * 512 + lane;
#pragma unroll
        for (int nt = 0; nt < 8; ++nt) {
            bf16x8 bf = w2v[wbase + nt * 64];
            acc0[nt] = __builtin_amdgcn_mfma_f32_16x16x32_bf16(af0, bf, acc0[nt], 0, 0, 0);
            acc1[nt] = __builtin_amdgcn_mfma_f32_16x16x32_bf16(af1, bf, acc1[nt], 0, 0, 0);
        }
    }

    // ---- LN2 + relu + layer-3 dot, store ----
    float b3v = b3[c];
    float v0 = ln2_dot(acc0, b2, g2, be2, W3, cb, colb, quad);
    float v1 = ln2_dot(acc1, b2, g2, be2, W3, cb, colb, quad);
    if (quad == 0) {
        if (e0 >= 0) out[e0] = v0 + b3v;
        if (e1 >= 0) out[e1] = v1 + b3v;
    }
}

extern "C" void kernel_launch(void* const* d_in, const int* in_sizes, int n_in,
                              void* d_out, int out_size, void* d_ws, size_t ws_size,
                              hipStream_t stream) {
    const float* x    = (const float*)d_in[0];
    const int*   ei   = (const int*)d_in[1];
    const float* e    = (const float*)d_in[2];
    const int*   vol  = (const int*)d_in[3];
    const float* W1   = (const float*)d_in[4];
    const float* b1   = (const float*)d_in[5];
    const float* g1   = (const float*)d_in[6];
    const float* be1  = (const float*)d_in[7];
    const float* W2   = (const float*)d_in[8];
    const float* b2   = (const float*)d_in[9];
    const float* g2   = (const float*)d_in[10];
    const float* be2  = (const float*)d_in[11];
    const float* W3   = (const float*)d_in[12];
    const float* b3   = (const float*)d_in[13];
    float* out = (float*)d_out;
    char* wsb = (char*)d_ws;

    hipMemsetAsync(wsb, 0, 256, stream);                                        // counters/cursors
    hipMemsetAsync(wsb + WS_LIST, 0xFF, (E_EDGES + 384) * sizeof(int), stream); // pad slots = -1

    k_wconv<<<1536, 256, 0, stream>>>(W1, W2,
        (unsigned short*)(wsb + WS_W1F), (unsigned short*)(wsb + WS_W2F));
    k_classify<<<(E_EDGES + 255) / 256, 256, 0, stream>>>(ei, vol,
        (signed char*)(wsb + WS_CMB), out, (int*)wsb);
    k_offsets<<<1, 64, 0, stream>>>((int*)wsb);
    k_scatter<<<(E_EDGES + 255) / 256, 256, 0, stream>>>(
        (const signed char*)(wsb + WS_CMB), (int*)(wsb + WS_LIST),
        (const int*)(wsb + 64), (int*)(wsb + 32));

    int maxt32 = E_EDGES / 32 + 6;
    int grid = (maxt32 + 3) / 4;
    k_mlp<<<grid, 256, 0, stream>>>(
        x, ei, e, (const int*)(wsb + 96), (const int*)(wsb + WS_LIST),
        (const unsigned short*)(wsb + WS_W1F), (const unsigned short*)(wsb + WS_W2F),
        b1, g1, be1, b2, g2, be2, W3, b3, out);
}